// Round 1
// 188.810 us; speedup vs baseline: 1.0411x; 1.0411x over previous
//
#include <hip/hip_runtime.h>
#include <hip/hip_bf16.h>
#include <math.h>

typedef __hip_bfloat16 bf16;
typedef __attribute__((ext_vector_type(8))) short bf16x8;
typedef __attribute__((ext_vector_type(4))) float f32x4;

#define B_SZ 4
#define SEQ  4096
#define DM   256
#define NST  16
#define NCHK 64
#define LC   (SEQ/NCHK)      /* 64 */
#define MT   (B_SZ*SEQ)      /* 16384 rows of (b,l) */
#define NLIN (B_SZ*16*256)   /* 16384 scan chains */

__device__ __forceinline__ float silu_f(float v){ return v / (1.f + __expf(-v)); }
__device__ __forceinline__ float softplus_f(float v){
  return (v > 15.f) ? v : __logf(1.f + __expf(v));
}
__device__ __forceinline__ short f2bf(float f){
  union { bf16 h; short s; } u; u.h = __float2bfloat16(f); return u.s;
}
__device__ __forceinline__ float bf2f(short s){
  union { unsigned int i; float f; } v;
  v.i = ((unsigned int)(unsigned short)s) << 16; return v.f;
}
__device__ __forceinline__ float4 bf4_to_f4(uint2 q){
  float4 f;
  f.x = bf2f((short)(q.x & 0xffffu)); f.y = bf2f((short)(q.x >> 16));
  f.z = bf2f((short)(q.y & 0xffffu)); f.w = bf2f((short)(q.y >> 16));
  return f;
}
__device__ __forceinline__ short4 f4_to_bf4(float4 f){
  short4 s; s.x = f2bf(f.x); s.y = f2bf(f.y); s.z = f2bf(f.z); s.w = f2bf(f.w);
  return s;
}

// async global->LDS 16B copy (no VGPR round-trip). LDS side must be
// wave-uniform base + lane*16 (m104/m108); global side is per-lane.
__device__ __forceinline__ void async_cp16(const short* g, short* l){
  __builtin_amdgcn_global_load_lds(
      (const __attribute__((address_space(1))) unsigned int*)g,
      (__attribute__((address_space(3))) unsigned int*)l, 16, 0, 0);
}

// DPP row_shr:N add step; after N=8,4,2,1 lane 15 of each row = row sum.
template<int CTRL>
__device__ __forceinline__ float dpp_add_step(float v){
  int x = __builtin_amdgcn_update_dpp(0, __float_as_int(v), CTRL, 0xf, 0xf, true);
  return v + __int_as_float(x);
}

// ---------------------------------------------------------------------------
// Input pre-conversion to bf16: w_in (768x256), w_o1 (256x256), hs (MT x 256).
// ---------------------------------------------------------------------------
__global__ __launch_bounds__(256)
void cvt_in_k(const float* __restrict__ w_in, const float* __restrict__ w_o1,
              const float* __restrict__ hs,
              short* __restrict__ w_in_b, short* __restrict__ w_o1_b,
              short* __restrict__ hsb)
{
  int i = blockIdx.x * 256 + threadIdx.x;     // 0..1114111
  if (i < 49152) {
    float4 q = *(const float4*)&w_in[i * 4];
    *(short4*)&w_in_b[i * 4] = f4_to_bf4(q);
  } else if (i < 65536) {
    int j = i - 49152;
    float4 q = *(const float4*)&w_o1[j * 4];
    *(short4*)&w_o1_b[j * 4] = f4_to_bf4(q);
  } else {
    int j = i - 65536;                        // 0..1048575
    float4 q = *(const float4*)&hs[(size_t)j * 4];
    *(short4*)&hsb[(size_t)j * 4] = f4_to_bf4(q);
  }
}

// ---------------------------------------------------------------------------
// K1 fused: xyz = hs @ in_proj_w^T  -> depthwise conv (k=1/3/5) -> SiLU
//   -> xcb/ycb/zcb, with NO xyzb round-trip through HBM.
// Each block computes 80 GEMM rows (m0-8 .. m0+71; 16-row halo each side,
// clamped loads) for a 128-col n-tile. n-tile lies entirely in one of
// x (n<256, k=1), y (256..511, k=3), z (512..767, k=5), so the conv type is
// block-uniform. Acc is rounded to bf16 (numerics identical to old xyzb
// path), staged col-major in LDS (stride 84 shorts, 8B-aligned b64 writes),
// then 256 threads (2 cols x 16 rows each) apply conv+SiLU and store.
// Zero-padding at l-boundaries: taps masked on l in [0,SEQ); b boundaries
// are multiples of SEQ so the mask is exact.
// ---------------------------------------------------------------------------
__global__ __launch_bounds__(256)
void mfma_gemm_conv_k(const short* __restrict__ Av,   // hsb (MT,256)
                      const short* __restrict__ Bw,   // w_in_b (768,256)
                      const float* __restrict__ wx, const float* __restrict__ bx,
                      const float* __restrict__ wy, const float* __restrict__ by,
                      const float* __restrict__ wz, const float* __restrict__ bz,
                      short* __restrict__ xout, short* __restrict__ yout,
                      short* __restrict__ zout)
{
  constexpr int RM = 80;                      // GEMM rows per block (64 + 2*8)
  __shared__ __align__(16) char smem_c[26624];
  short* As = (short*)smem_c;                 // RM x 64 bf16 = 10240 B
  short* Bs = (short*)(smem_c + 10240);       // 128 x 64 bf16 = 16384 B
  const int tid  = threadIdx.x;
  const int wave = tid >> 6, lane = tid & 63;
  const int quad = lane >> 4, l16 = lane & 15;
  const int wn = wave * 32;
  const int m0 = blockIdx.x * 64, n0 = blockIdx.y * 128;

  f32x4 acc[5][2] = {};

  for (int k0 = 0; k0 < 256; k0 += 64) {
    #pragma unroll
    for (int p = 0; p < 3; p++) {             // A chunks: 80 rows * 8 = 640
      int id = p * 256 + tid;
      if (id < RM * 8) {                      // wave-uniform cut (640 = 10*64)
        int row = id >> 3, slot = id & 7;
        int gch = slot ^ (row & 7);
        int gm = m0 - 8 + row;
        gm = gm < 0 ? 0 : (gm > MT - 1 ? MT - 1 : gm);
        async_cp16(Av + (size_t)gm * 256 + k0 + gch * 8,
                   &As[row * 64 + slot * 8]);
      }
    }
    #pragma unroll
    for (int p = 0; p < 4; p++) {             // B chunks (128 rows)
      int id = p * 256 + tid;
      int row = id >> 3, slot = id & 7;
      int gch = slot ^ (row & 7);
      async_cp16(Bw + (size_t)(n0 + row) * 256 + k0 + gch * 8,
                 &Bs[row * 64 + slot * 8]);
    }
    __syncthreads();                          // drains vmcnt (DMA) for all waves
    #pragma unroll
    for (int ks = 0; ks < 2; ks++) {          // two 32-k steps per BK=64
      bf16x8 fa[5], fb[2];
      int sa = (ks * 4 + quad) ^ (l16 & 7);
      #pragma unroll
      for (int i = 0; i < 5; i++)
        fa[i] = *(const bf16x8*)&As[(i * 16 + l16) * 64 + sa * 8];
      #pragma unroll
      for (int j = 0; j < 2; j++)
        fb[j] = *(const bf16x8*)&Bs[(wn + j * 16 + l16) * 64 + sa * 8];
      #pragma unroll
      for (int i = 0; i < 5; i++)
        #pragma unroll
        for (int j = 0; j < 2; j++)
          acc[i][j] = __builtin_amdgcn_mfma_f32_16x16x32_bf16(fa[i], fb[j], acc[i][j], 0, 0, 0);
    }
    __syncthreads();
  }

  // ---- stage acc tile into LDS, col-major [128][84] bf16 (reuses As/Bs) ----
  short* Ts = (short*)smem_c;                 // 128*84*2 = 21504 B <= 26624
  #pragma unroll
  for (int i = 0; i < 5; i++) {
    #pragma unroll
    for (int j = 0; j < 2; j++) {
      int col = wn + j * 16 + l16;            // 0..127
      int row = i * 16 + quad * 4;            // tile row (gm = m0-8+row)
      short4 v;
      v.x = f2bf(acc[i][j][0]); v.y = f2bf(acc[i][j][1]);
      v.z = f2bf(acc[i][j][2]); v.w = f2bf(acc[i][j][3]);
      *(short4*)&Ts[col * 84 + row] = v;      // 8B-aligned (84*2 % 8 == 0)
    }
  }
  __syncthreads();

  // ---- conv + SiLU + store: thread = 2 cols x 16 out rows ----
  const int cp = tid & 63, rg = tid >> 6;
  const int lc0 = cp * 2;                     // local col 0,2,..,126
  const int lr0 = rg * 16;                    // local out row base 0..48
  const int lbase = (m0 & (SEQ - 1)) + lr0;   // l of out row t=0 (no wrap in-block)
  float ta[24], tb[24];                       // tile rows lr0+4 .. lr0+27
  {
    const short* q0 = &Ts[lc0 * 84 + lr0 + 4];
    #pragma unroll
    for (int q = 0; q < 6; q++) {
      short4 a = *(const short4*)&q0[q * 4];
      short4 b = *(const short4*)&q0[84 + q * 4];
      ta[q*4+0] = bf2f(a.x); ta[q*4+1] = bf2f(a.y);
      ta[q*4+2] = bf2f(a.z); ta[q*4+3] = bf2f(a.w);
      tb[q*4+0] = bf2f(b.x); tb[q*4+1] = bf2f(b.y);
      tb[q*4+2] = bf2f(b.z); tb[q*4+3] = bf2f(b.w);
    }
  }
  // out row t (0..15): tile row = lr0+8+t+dj -> reg idx = t + dj + 4
  const int type = n0 >> 8;                   // 0:x(k=1) 1:y(k=3) 2:z(k=5)
  const int gq = n0 + lc0 - type * 256;       // channel 0..254 (even)
  if (type == 0) {
    float w0 = wx[gq], w1 = wx[gq + 1];
    float b0 = bx[gq], b1 = bx[gq + 1];
    #pragma unroll
    for (int t = 0; t < 16; t++) {
      short2 o;
      o.x = f2bf(silu_f(fmaf(ta[t + 4], w0, b0)));
      o.y = f2bf(silu_f(fmaf(tb[t + 4], w1, b1)));
      *(short2*)&xout[(size_t)(m0 + lr0 + t) * 256 + gq] = o;
    }
  } else if (type == 1) {
    float w0[3], w1[3];
    #pragma unroll
    for (int j = 0; j < 3; j++) { w0[j] = wy[gq*3 + j]; w1[j] = wy[(gq+1)*3 + j]; }
    float b0 = by[gq], b1 = by[gq + 1];
    #pragma unroll
    for (int t = 0; t < 16; t++) {
      float a0 = b0, a1 = b1;
      #pragma unroll
      for (int j = 0; j < 3; j++) {
        int l = lbase + t + j - 1;
        bool ok = ((unsigned)l < SEQ);
        a0 = fmaf(ok ? ta[t + 3 + j] : 0.f, w0[j], a0);
        a1 = fmaf(ok ? tb[t + 3 + j] : 0.f, w1[j], a1);
      }
      short2 o; o.x = f2bf(silu_f(a0)); o.y = f2bf(silu_f(a1));
      *(short2*)&yout[(size_t)(m0 + lr0 + t) * 256 + gq] = o;
    }
  } else {
    float w0[5], w1[5];
    #pragma unroll
    for (int j = 0; j < 5; j++) { w0[j] = wz[gq*5 + j]; w1[j] = wz[(gq+1)*5 + j]; }
    float b0 = bz[gq], b1 = bz[gq + 1];
    #pragma unroll
    for (int t = 0; t < 16; t++) {
      float a0 = b0, a1 = b1;
      #pragma unroll
      for (int j = 0; j < 5; j++) {
        int l = lbase + t + j - 2;
        bool ok = ((unsigned)l < SEQ);
        a0 = fmaf(ok ? ta[t + 2 + j] : 0.f, w0[j], a0);
        a1 = fmaf(ok ? tb[t + 2 + j] : 0.f, w1[j], a1);
      }
      short2 o; o.x = f2bf(silu_f(a0)); o.y = f2bf(silu_f(a1));
      *(short2*)&zout[(size_t)(m0 + lr0 + t) * 256 + gq] = o;
    }
  }
}

// ---------------------------------------------------------------------------
// MFMA bf16 GEMM (K8 only now), BM=64, BN=128, BK=64. XOR-swizzled slots.
// EPI 2: (acc * zc[m,n] * cwx[n] + bias[n]) (zc bf16).
// ---------------------------------------------------------------------------
template<int EPI, bool OBF, int BM>
__global__ __launch_bounds__(256)
void mfma_gemm_k(const short* __restrict__ Av, const short* __restrict__ Bw,
                 void* __restrict__ Outv, int N, int K,
                 const float* __restrict__ bias, const short* __restrict__ zc,
                 const float* __restrict__ cwx)
{
  constexpr int BN = 128, BK = 64;
  constexpr int JF = (BM == 64) ? 2 : 4;      // j-fragments per wave
  __shared__ short As[BM * BK];
  __shared__ short Bs[BN * BK];
  const int tid  = threadIdx.x;
  const int wave = tid >> 6, lane = tid & 63;
  const int quad = lane >> 4, l16 = lane & 15;
  const int wm = (BM == 64) ? 0 : (wave & 1) * 64;
  const int wn = (BM == 64) ? wave * 32 : (wave >> 1) * 64;
  const int m0 = blockIdx.x * BM, n0 = blockIdx.y * BN;

  f32x4 acc[4][JF] = {};

  for (int k0 = 0; k0 < K; k0 += BK) {
    #pragma unroll
    for (int p = 0; p < BM * 8 / 256; p++) {   // A chunks
      int id = p * 256 + tid;
      int row = id >> 3, slot = id & 7;
      int gch = slot ^ (row & 7);
      async_cp16(Av + (size_t)(m0 + row) * K + k0 + gch * 8,
                 &As[row * 64 + slot * 8]);
    }
    #pragma unroll
    for (int p = 0; p < 4; p++) {              // B chunks (128 rows)
      int id = p * 256 + tid;
      int row = id >> 3, slot = id & 7;
      int gch = slot ^ (row & 7);
      async_cp16(Bw + (size_t)(n0 + row) * K + k0 + gch * 8,
                 &Bs[row * 64 + slot * 8]);
    }
    __syncthreads();                    // drains vmcnt (DMA) for all waves
    #pragma unroll
    for (int ks = 0; ks < 2; ks++) {    // two 32-k steps per BK=64
      bf16x8 fa[4], fb[JF];
      int sa = (ks * 4 + quad) ^ (l16 & 7);
      #pragma unroll
      for (int i = 0; i < 4; i++)
        fa[i] = *(const bf16x8*)&As[(wm + i * 16 + l16) * 64 + sa * 8];
      #pragma unroll
      for (int j = 0; j < JF; j++)
        fb[j] = *(const bf16x8*)&Bs[(wn + j * 16 + l16) * 64 + sa * 8];
      #pragma unroll
      for (int i = 0; i < 4; i++)
        #pragma unroll
        for (int j = 0; j < JF; j++)
          acc[i][j] = __builtin_amdgcn_mfma_f32_16x16x32_bf16(fa[i], fb[j], acc[i][j], 0, 0, 0);
    }
    __syncthreads();
  }

  #pragma unroll
  for (int i = 0; i < 4; i++) {
    #pragma unroll
    for (int j = 0; j < JF; j++) {
      int n = n0 + wn + j * 16 + l16;
      #pragma unroll
      for (int r = 0; r < 4; r++) {
        int m = m0 + wm + i * 16 + quad * 4 + r;
        float v = acc[i][j][r];
        if constexpr (EPI == 2)
          v = v * bf2f(zc[(size_t)m * N + n]) * cwx[n] + bias[n];
        if constexpr (OBF) ((short*)Outv)[(size_t)m * N + n] = f2bf(v);
        else               ((float*)Outv)[(size_t)m * N + n] = v;
      }
    }
  }
}

// ---------------------------------------------------------------------------
// Fused K3+K4 (TM=32): xdbl = xc @ x_proj_w^T; dtv = softplus(dt_r@wdt^T+2b).
// ---------------------------------------------------------------------------
__global__ __launch_bounds__(256)
void gemm34_k(const short* __restrict__ xcb,
              const float* __restrict__ Bw,
              const float* __restrict__ wdt,
              const float* __restrict__ bdt,
              float* __restrict__ xdbl,
              float* __restrict__ dtv)
{
  constexpr int TM = 32, TK = 16, NN = 48;
  __shared__ __align__(16) float As[TK][TM + 4];
  __shared__ __align__(16) float Bs[TK][64 + 4];
  __shared__ __align__(16) float dt_s[TM][20];
  __shared__ __align__(16) float wdt_s[256][20];
  const int tid = threadIdx.x;
  const int tn = tid & 15, tm = tid >> 4;
  const int m0 = blockIdx.x * TM;
  float acc[2][4] = {};
  const int mlA = tid >> 3, kdA = (tid & 7) * 2;
  const int mlB = tid >> 2, kqB = (tid & 3) * 4;

  {
    float4 q0 = *(const float4*)&wdt[tid * 16 + 0];
    float4 q1 = *(const float4*)&wdt[tid * 16 + 4];
    float4 q2 = *(const float4*)&wdt[tid * 16 + 8];
    float4 q3 = *(const float4*)&wdt[tid * 16 + 12];
    *(float4*)&wdt_s[tid][0]  = q0;
    *(float4*)&wdt_s[tid][4]  = q1;
    *(float4*)&wdt_s[tid][8]  = q2;
    *(float4*)&wdt_s[tid][12] = q3;
  }

  for (int k0 = 0; k0 < 256; k0 += TK) {
    {
      size_t off = (size_t)(m0 + mlA) * 256 + k0 + kdA;
      unsigned int v = *(const unsigned int*)(xcb + off);
      As[kdA + 0][mlA] = bf2f((short)(v & 0xffffu));
      As[kdA + 1][mlA] = bf2f((short)(v >> 16));
    }
    {
      float v0 = 0.f, v1 = 0.f, v2 = 0.f, v3 = 0.f;
      if (mlB < NN) {
        float4 q = *(const float4*)(Bw + (size_t)mlB * 256 + k0 + kqB);
        v0 = q.x; v1 = q.y; v2 = q.z; v3 = q.w;
      }
      Bs[kqB+0][mlB] = v0; Bs[kqB+1][mlB] = v1; Bs[kqB+2][mlB] = v2; Bs[kqB+3][mlB] = v3;
    }
    __syncthreads();
    #pragma unroll
    for (int k = 0; k < TK; k++) {
      float2 av = *(const float2*)&As[k][tm << 1];
      float4 bv = *(const float4*)&Bs[k][tn << 2];
      float a[2] = {av.x, av.y};
      float b[4] = {bv.x, bv.y, bv.z, bv.w};
      #pragma unroll
      for (int i = 0; i < 2; i++)
        #pragma unroll
        for (int j = 0; j < 4; j++)
          acc[i][j] = fmaf(a[i], b[j], acc[i][j]);
    }
    __syncthreads();
  }

  #pragma unroll
  for (int i = 0; i < 2; i++) {
    int m = m0 + (tm << 1) + i;
    #pragma unroll
    for (int j = 0; j < 4; j++) {
      int n = (tn << 2) + j;
      float v = acc[i][j];
      if (n < NN) xdbl[(size_t)m * NN + n] = v;
      if (tn < 4) dt_s[(tm << 1) + i][n] = v;
    }
  }
  __syncthreads();

  const int c0 = tid & 63, rg = tid >> 6;
  float w[4][16];
  float bb[4];
  #pragma unroll
  for (int cc = 0; cc < 4; cc++) {
    int col = cc * 64 + c0;
    #pragma unroll
    for (int q = 0; q < 4; q++) {
      float4 t = *(const float4*)&wdt_s[col][q * 4];
      w[cc][q*4+0] = t.x; w[cc][q*4+1] = t.y; w[cc][q*4+2] = t.z; w[cc][q*4+3] = t.w;
    }
    bb[cc] = 2.f * bdt[col];
  }
  #pragma unroll
  for (int rr = 0; rr < 8; rr++) {
    int row = rg * 8 + rr;
    float dr[16];
    #pragma unroll
    for (int q = 0; q < 4; q++) {
      float4 t = *(const float4*)&dt_s[row][q * 4];
      dr[q*4+0] = t.x; dr[q*4+1] = t.y; dr[q*4+2] = t.z; dr[q*4+3] = t.w;
    }
    #pragma unroll
    for (int cc = 0; cc < 4; cc++) {
      float s = bb[cc];
      #pragma unroll
      for (int k = 0; k < 16; k++) s = fmaf(dr[k], w[cc][k], s);
      dtv[(size_t)(m0 + row) * 256 + cc * 64 + c0] = softplus_f(s);
    }
  }
}

// ---------------------------------------------------------------------------
// Chunked selective scan, t-unrolled x4, LDS transposed [channel][t].
// Chunk-state arrays in transposed (coalesced) layout cidx = ch*NLIN + lin.
// Pass C writeback fuses the p*y elementwise product (reads ycb).
// ---------------------------------------------------------------------------
template<bool PASSC>
__global__ __launch_bounds__(256)
void scan_k(const short* __restrict__ xcb,    // u (bf16), (MT,256)
            const float* __restrict__ dtv,    // delta, (MT,256)
            const float* __restrict__ xdbl,   // (MT,48): [dt_r | B | C]
            const float* __restrict__ A_log,
            const float* __restrict__ Dp,
            const float* __restrict__ Hstart,
            float* __restrict__ Pbuf, float* __restrict__ hfbuf,
            const short* __restrict__ ycb,    // y-gate (bf16), pass C
            short* __restrict__ poutb)        // pass C out (bf16): p*yc
{
  __shared__ __align__(16) float2 du2_s[16 * 66];             // [ch][t]
  __shared__ __align__(16) float2 BC_s [PASSC ? 16 * 66 : 2]; // [n][t]
  __shared__ __align__(16) float  Bc_s [PASSC ? 4 : 16 * 68]; // [n][t] (pass A)
  __shared__ __align__(16) float  y_s  [PASSC ? 16 * 68 : 4]; // [ch][t]
  const int tid = threadIdx.x;
  const int n = tid & 15, dl = tid >> 4;
  const int ch = blockIdx.x;
  const int d0 = blockIdx.y * 16;
  const int b  = blockIdx.z;
  const int d  = d0 + dl;
  const int t0 = ch * LC;
  const size_t brow = (size_t)b * SEQ;
  const size_t cidx = (size_t)ch * NLIN + ((size_t)b * 16 + blockIdx.y) * 256 + tid;

  float u_r[4];
  #pragma unroll
  for (int i = 0; i < 4; i++) {               // cooperative coalesced staging
    int t = (tid >> 4) + i * 16;
    int dd = tid & 15;
    size_t row = brow + t0 + t;
    float uval = bf2f(xcb[row * 256 + d0 + dd]);
    float dval = dtv[row * 256 + d0 + dd];
    du2_s[dd * 66 + t] = make_float2(dval, dval * uval);
    if constexpr (PASSC) {
      BC_s[dd * 66 + t] = make_float2(xdbl[row * 48 + 16 + dd],
                                      xdbl[row * 48 + 32 + dd]);
      u_r[i] = uval;
    } else {
      Bc_s[dd * 68 + t] = xdbl[row * 48 + 16 + dd];
    }
  }
  __syncthreads();

  const float A_dn = -__expf(A_log[d * NST + n]);

  float h = PASSC ? Hstart[cidx] : 0.f;
  float P = 1.f;
  for (int t4 = 0; t4 < LC; t4 += 4) {
    float4 a = *(const float4*)&du2_s[dl * 66 + t4];      // {dt0,du0,dt1,du1}
    float4 c = *(const float4*)&du2_s[dl * 66 + t4 + 2];  // {dt2,du2,dt3,du3}
    float dA[4], du[4];
    dA[0] = __expf(a.x * A_dn); du[0] = a.y;
    dA[1] = __expf(a.z * A_dn); du[1] = a.w;
    dA[2] = __expf(c.x * A_dn); du[2] = c.y;
    dA[3] = __expf(c.z * A_dn); du[3] = c.w;
    if constexpr (!PASSC) {
      float4 f = *(const float4*)&Bc_s[n * 68 + t4];      // B t4..t4+3
      float Bv[4] = {f.x, f.y, f.z, f.w};
      #pragma unroll
      for (int j = 0; j < 4; j++) {
        h = fmaf(dA[j], h, du[j] * Bv[j]);
        P *= dA[j];
      }
    } else {
      float4 e = *(const float4*)&BC_s[n * 66 + t4];      // {B0,C0,B1,C1}
      float4 g = *(const float4*)&BC_s[n * 66 + t4 + 2];  // {B2,C2,B3,C3}
      float Bv[4] = {e.x, e.z, g.x, g.z};
      float Cv[4] = {e.y, e.w, g.y, g.w};
      float yv[4];
      #pragma unroll
      for (int j = 0; j < 4; j++) {
        h = fmaf(dA[j], h, du[j] * Bv[j]);
        yv[j] = h * Cv[j];
      }
      #pragma unroll
      for (int j = 0; j < 4; j++) yv[j] = dpp_add_step<0x118>(yv[j]); // shr8
      #pragma unroll
      for (int j = 0; j < 4; j++) yv[j] = dpp_add_step<0x114>(yv[j]); // shr4
      #pragma unroll
      for (int j = 0; j < 4; j++) yv[j] = dpp_add_step<0x112>(yv[j]); // shr2
      #pragma unroll
      for (int j = 0; j < 4; j++) yv[j] = dpp_add_step<0x111>(yv[j]); // shr1
      if (n == 15)
        *(float4*)&y_s[dl * 68 + t4] = make_float4(yv[0], yv[1], yv[2], yv[3]);
    }
  }

  if constexpr (!PASSC) {
    Pbuf[cidx] = P;                           // coalesced (transposed layout)
    hfbuf[cidx] = h;
  } else {
    __syncthreads();
    const float Dval = Dp[d0 + n];
    #pragma unroll
    for (int i = 0; i < 4; i++) {             // coalesced writeback, fused *yc
      int t = (tid >> 4) + i * 16;
      size_t row = brow + t0 + t;
      float p = fmaf(Dval, u_r[i], y_s[n * 68 + t]);
      float yg = bf2f(ycb[row * 256 + d0 + n]);
      poutb[row * 256 + d0 + n] = f2bf(p * yg);
    }
  }
}

// serial combine across the 64 chunks; transposed layout -> coalesced.
__global__ __launch_bounds__(256)
void scan_mid_k(const float* __restrict__ Pbuf, const float* __restrict__ hfbuf,
                float* __restrict__ Hstart)
{
  int lin = blockIdx.x * 256 + threadIdx.x;   // 0..16383
  float H = 0.f;
  for (int c = 0; c < NCHK; c++) {
    size_t idx = (size_t)c * NLIN + lin;
    Hstart[idx] = H;
    H = Pbuf[idx] * H + hfbuf[idx];
  }
}

// ---------------------------------------------------------------------------
extern "C" void kernel_launch(void* const* d_in, const int* in_sizes, int n_in,
                              void* d_out, int out_size, void* d_ws, size_t ws_size,
                              hipStream_t stream)
{
  const float* hs    = (const float*)d_in[0];
  const float* w_in  = (const float*)d_in[1];
  const float* w_xp  = (const float*)d_in[2];
  const float* w_dt  = (const float*)d_in[3];
  const float* b_dt  = (const float*)d_in[4];
  const float* A_log = (const float*)d_in[5];
  const float* Dp    = (const float*)d_in[6];
  const float* w_o1  = (const float*)d_in[7];
  const float* cwx   = (const float*)d_in[8];
  const float* cbx   = (const float*)d_in[9];
  const float* cwy   = (const float*)d_in[10];
  const float* cby   = (const float*)d_in[11];
  const float* cwz   = (const float*)d_in[12];
  const float* cbz   = (const float*)d_in[13];

  char* wsb = (char*)d_ws;
  short* xcb  = (short*)wsb;                            // MT*256 bf16
  short* ycb  = xcb + (size_t)MT * 256;
  short* zcb  = ycb + (size_t)MT * 256;
  short* pbufb= zcb + (size_t)MT * 256;                 // p*yc (bf16)
  short* w_in_b = pbufb + (size_t)MT * 256;             // 768*256 bf16
  short* w_o1_b = w_in_b + 768 * 256;                   // 256*256 bf16
  short* hsb  = w_o1_b + 256 * 256;                     // MT*256 bf16
  float* xdbl = (float*)(hsb + (size_t)MT * 256 + 128); // MT*48 fp32
  float* dtv  = xdbl + (size_t)MT * 48;                 // MT*256 fp32
  float* Pb   = dtv  + (size_t)MT * 256;                // 1M fp32
  float* hf   = Pb   + (size_t)NCHK * NLIN;
  float* Hs   = hf   + (size_t)NCHK * NLIN;

  dim3 blk(256);

  // K0: weights + hs -> bf16
  cvt_in_k<<<dim3(4352), blk, 0, stream>>>(w_in, w_o1, hs, w_in_b, w_o1_b, hsb);

  // K1 (fused): xyz = hs @ in_proj_w^T -> dwconv -> SiLU -> xcb/ycb/zcb
  mfma_gemm_conv_k<<<dim3(MT / 64, 768 / 128), blk, 0, stream>>>(
      hsb, w_in_b, cwx, cbx, cwy, cby, cwz, cbz, xcb, ycb, zcb);

  // K3+K4 fused
  gemm34_k<<<dim3(MT / 32), blk, 0, stream>>>(
      xcb, w_xp, w_dt, b_dt, xdbl, dtv);

  // K5-7: chunked selective scan -> pbufb = (scan out)*yc (bf16)
  scan_k<false><<<dim3(NCHK, DM / 16, B_SZ), blk, 0, stream>>>(
      xcb, dtv, xdbl, A_log, Dp, nullptr, Pb, hf, nullptr, nullptr);
  scan_mid_k<<<dim3(NLIN / 256), blk, 0, stream>>>(Pb, hf, Hs);
  scan_k<true><<<dim3(NCHK, DM / 16, B_SZ), blk, 0, stream>>>(
      xcb, dtv, xdbl, A_log, Dp, Hs, nullptr, nullptr, ycb, pbufb);

  // K8: out = (pbufb @ out_proj1_w^T) * zc * cwx + cbx  (BM=64 -> 512 blocks)
  mfma_gemm_k<2, false, 64><<<dim3(MT / 64, 256 / 128), blk, 0, stream>>>(
      pbufb, w_o1_b, d_out, 256, 256, cbx, zcb, cwx);
}